// Round 9
// baseline (355.848 us; speedup 1.0000x reference)
//
#include <hip/hip_runtime.h>
#include <hip/hip_bf16.h>
#include <stdint.h>

#define N_NODES 50000
#define N_EDGES 500000
#define R_REL 8
#define HID 128
#define KIN 128              // input features per slab
#define KOUT 1152            // 9*128: concat K dim (W_0..W_7 | root)
#define N8 400000            // N_NODES * R_REL composite buckets
#define NUM_GRAPHS 64
#define NUM_CLASSES 16

#define BN 64                // dst-nodes per fused block
#define LDA 1160             // A row stride in shorts (2320 B)
#define NBLK 782             // ceil(50000/64)

typedef __attribute__((ext_vector_type(8))) short bf16x8;
typedef __attribute__((ext_vector_type(4))) float f32x4;

// ---------- helpers ----------
__device__ __forceinline__ uint16_t f2bf(float f) {
  uint32_t u = __float_as_uint(f);
  u += 0x7FFFu + ((u >> 16) & 1u);   // RNE
  return (uint16_t)(u >> 16);
}
__device__ __forceinline__ float bf2f(uint32_t b) {
  return __uint_as_float(b << 16);
}
__device__ __forceinline__ uint32_t pack2bf(float a, float b) {
  return (uint32_t)f2bf(a) | ((uint32_t)f2bf(b) << 16);
}
#define MFMA(a, b, c) __builtin_amdgcn_mfma_f32_16x16x32_bf16((a), (b), (c), 0, 0, 0)

// ---------- merged prep: hist | bounds | weightprep (LDS-staged) | x->bf16 ----------
#define HIST_B 1954
#define BND_B 196
#define WP_B 72             // 2 matrices x 36 kc-chunks
#define CVT_B 3125          // N_NODES*HID/8 / 256
__global__ __launch_bounds__(256) void k_prep(const int* __restrict__ ei, const int* __restrict__ et,
                                              int* __restrict__ deg8,
                                              const int* __restrict__ batch,
                                              int* __restrict__ gs, int* __restrict__ ge,
                                              const float* __restrict__ W1, const float* __restrict__ root1,
                                              uint16_t* __restrict__ Wf1,
                                              const float* __restrict__ W2, const float* __restrict__ root2,
                                              uint16_t* __restrict__ Wf2,
                                              const float* __restrict__ x, uint16_t* __restrict__ xb) {
  int b = blockIdx.x;
  int t = threadIdx.x;
  if (b < HIST_B) {                                 // (dst,rel) edge histogram (400K buckets)
    int i = b * 256 + t;
    if (i < N_EDGES) atomicAdd(&deg8[ei[N_EDGES + i] * R_REL + et[i]], 1);
    return;
  }
  b -= HIST_B;
  if (b < BND_B) {                                  // graph boundaries (batch sorted)
    int i = b * 256 + t;
    if (i < N_NODES) {
      int g = batch[i];
      if (i == 0) gs[g] = 0;
      else { int pg = batch[i - 1]; if (pg != g) { ge[pg] = i; gs[g] = i; } }
      if (i == N_NODES - 1) ge[g] = N_NODES;
    }
    return;
  }
  b -= BND_B;
  if (b < WP_B) {
    // weight prep, LDS-staged: block handles one kc-chunk (32 K-rows x 128 cols) of one matrix.
    __shared__ float lw[32 * 129];
    const float* W    = (b < 36) ? W1 : W2;
    const float* root = (b < 36) ? root1 : root2;
    uint16_t*    Wf   = (b < 36) ? Wf1 : Wf2;
    int kc = (b < 36) ? b : b - 36;
    #pragma unroll
    for (int j = 0; j < 4; ++j) {
      int fi = j * 256 + t;                  // float4 slot over 32 rows x 32 f4
      int row = fi >> 5, c4 = fi & 31;
      int kk = kc * 32 + row;
      int s = kk >> 7, k = kk & 127;
      const float* src = (s < R_REL) ? (W + ((size_t)s * KIN + k) * HID) : (root + (size_t)k * HID);
      float4 v = *(const float4*)(src + c4 * 4);
      lw[row * 129 + c4 * 4 + 0] = v.x;
      lw[row * 129 + c4 * 4 + 1] = v.y;
      lw[row * 129 + c4 * 4 + 2] = v.z;
      lw[row * 129 + c4 * 4 + 3] = v.w;
    }
    __syncthreads();
    #pragma unroll
    for (int p = 0; p < 2; ++p) {
      int slot = p * 256 + t;                // 8 frags x 64 lanes
      int nt = slot >> 6, L = slot & 63;
      int quad = L >> 4, l16 = L & 15;
      uint16_t tmp[8];
      #pragma unroll
      for (int e = 0; e < 8; ++e)
        tmp[e] = f2bf(lw[(quad * 8 + e) * 129 + nt * 16 + l16]);
      uint4 o;
      o.x = (uint32_t)tmp[0] | ((uint32_t)tmp[1] << 16);
      o.y = (uint32_t)tmp[2] | ((uint32_t)tmp[3] << 16);
      o.z = (uint32_t)tmp[4] | ((uint32_t)tmp[5] << 16);
      o.w = (uint32_t)tmp[6] | ((uint32_t)tmp[7] << 16);
      *(uint4*)(Wf + ((size_t)(kc * 8 + nt) * 512 + (size_t)L * 8)) = o;
    }
    return;
  }
  b -= WP_B;
  {                                                 // x (fp32) -> xb (bf16), 8 elems/thread
    int i = b * 256 + t;                            // < 800000 exact
    const float4* p = (const float4*)x + (size_t)i * 2;
    float4 a = p[0], c = p[1];
    uint4 o;
    o.x = pack2bf(a.x, a.y); o.y = pack2bf(a.z, a.w);
    o.z = pack2bf(c.x, c.y); o.w = pack2bf(c.z, c.w);
    *(uint4*)(xb + (size_t)i * 8) = o;
  }
}

// ---------- single-kernel scan over 400K (dst,rel) buckets ----------
// Order-free global base via one atomicAdd per block: bucket RANGES get permuted across
// 1024-bucket scan chunks, but each fused block's 512 buckets live inside ONE chunk, so
// within-block ordering (what the fused kernel needs) is preserved. Explicit per-fused-block
// end offsets are emitted in ends[] (fused block f = edges [offs8[f*512], ends[f]) ).
__global__ __launch_bounds__(256) void k_scan(const int* __restrict__ deg8, int* __restrict__ offs8,
                                              int* __restrict__ nxt, int* __restrict__ ends,
                                              int* __restrict__ gcount) {
  __shared__ int sh[256];
  __shared__ int base_sh;
  int t = threadIdx.x;
  int base = blockIdx.x * 1024 + t * 4;
  int v[4]; int s = 0;
  #pragma unroll
  for (int i = 0; i < 4; ++i) { int idx = base + i; v[i] = (idx < N8) ? deg8[idx] : 0; s += v[i]; }
  sh[t] = s;
  __syncthreads();
  for (int d = 1; d < 256; d <<= 1) {
    int add = (t >= d) ? sh[t - d] : 0;
    __syncthreads();
    sh[t] += add;
    __syncthreads();
  }
  if (t == 0) base_sh = atomicAdd(gcount, sh[255]);
  __syncthreads();
  int gbase = base_sh;
  int run = gbase + sh[t] - s;
  #pragma unroll
  for (int i = 0; i < 4; ++i) {
    int idx = base + i;
    if (idx < N8) { offs8[idx] = run; nxt[idx] = run; }
    run += v[i];
  }
  // fused-block ends: this chunk = fused blocks 2b (buckets 0..511) and 2b+1 (512..1023)
  if (t == 127) ends[2 * blockIdx.x] = gbase + sh[127];
  if (t == 255) ends[2 * blockIdx.x + 1] = gbase + sh[255];
}

// scatter into (dst,rel) buckets: within each fused block the stream is (dst,rel)-grouped.
// epack = src | rel<<16 | (dst&63)<<19
__global__ __launch_bounds__(256) void k_scatter(const int* __restrict__ ei, const int* __restrict__ et,
                                                 int* __restrict__ nxt, uint32_t* __restrict__ epack) {
  int i = blockIdx.x * 256 + threadIdx.x;
  if (i < N_EDGES) {
    int rel = et[i];
    int dst = ei[N_EDGES + i];
    int p = atomicAdd(&nxt[dst * R_REL + rel], 1);
    epack[p] = (uint32_t)ei[i] | ((uint32_t)rel << 16) | ((uint32_t)(dst & 63) << 19);
  }
}

// ---------- phase-1 macros: branch-free extract+gather, scalar-branch accumulate ----------
#define EXTGATH(pc, sv, vv)                                                   \
  {                                                                           \
    _Pragma("unroll")                                                         \
    for (int i_ = 0; i_ < 16; ++i_)                                           \
      sv[i_] = (uint32_t)__builtin_amdgcn_readlane((int)(pc), i_);            \
    _Pragma("unroll")                                                         \
    for (int i_ = 0; i_ < 16; ++i_) {                                         \
      uint32_t s_ = sv[i_] & 0xFFFFu;                                         \
      s_ = (s_ < (uint32_t)N_NODES) ? s_ : 0u;                                \
      vv[i_] = *(const uint32_t*)(hin + (size_t)s_ * HID + voff);             \
    }                                                                         \
    __builtin_amdgcn_sched_barrier(0);                                        \
  }

#define PROCESS(sv, vv, gbase_)                                               \
  {                                                                           \
    int m_ = min(16, blkEnd - (gbase_));                                      \
    _Pragma("unroll")                                                         \
    for (int i_ = 0; i_ < 16; ++i_) {                                         \
      if (i_ >= m_) break;                                                    \
      uint32_t k_ = sv[i_] >> 16;                                             \
      if (k_ == cur) {                                                        \
        uint32_t v_ = vv[i_];                                                 \
        ax += bf2f(v_ & 0xFFFFu); ay += bf2f(v_ >> 16); ++ct;                 \
      } else if (k_ != kskip) {                                               \
        if (cur != 0xFFFFFFFFu) {                                             \
          float iv_ = __builtin_amdgcn_rcpf((float)ct);                       \
          *(uint32_t*)(As + (size_t)(cur >> 3) * LDA + (cur & 7u) * HID + voff) = \
              pack2bf(ax * iv_, ay * iv_);                                    \
        }                                                                     \
        if ((gbase_) + i_ >= e1) { done = true; cur = 0xFFFFFFFFu; break; }   \
        cur = k_;                                                             \
        uint32_t v_ = vv[i_];                                                 \
        ax = bf2f(v_ & 0xFFFFu); ay = bf2f(v_ >> 16); ct = 1;                 \
      }                                                                       \
    }                                                                         \
  }

// ---------- fused layer: sorted-stream aggregate -> split-K MFMA transform ----------
// Block = 64 dst nodes, 1024 threads (16 waves), LDS As[64][1160] bf16 (148480 B, 1 block/CU).
// Phase 1: 16 waves stream the block's edge range [offs8[blk*512], ends[blk]) in flat chunks.
//   2-stage ping-pong pipeline: batch k+1's 16 gathers issue (sched_barrier-pinned) while
//   batch k is processed -- L3 gather latency hidden under processing. Scalar-branch
//   flush-on-key-change (key = (loc<<3)|rel), mean 1/cnt at flush.
// Phase 2: GEMM out[64,128] = As[64,1152] @ Wcat. wave = (mh=w>>3, nt=(w>>2)&1, kh=w&3):
//   rows mh*32..+32, cols nt*64..+64, K-quarter kh (9 kc). B depth-2 prefetch; each B-frag
//   feeds 2 m-frags, each A-frag 2 nt-waves (2.4x less LDS A-traffic than 8-way nt split).
//   4-way split-K reduced through As reused as scratch (3 x 32 KB).
// MODE 0: write bf16 hout. MODE 1: fused global-mean-pool partials into psum.
template<int MODE>
__global__ __launch_bounds__(1024, 4) void k_fused(const uint16_t* __restrict__ hin,
                                                   const uint32_t* __restrict__ epack,
                                                   const int* __restrict__ offs8,
                                                   const int* __restrict__ ends,
                                                   const uint16_t* __restrict__ Wf,
                                                   const float* __restrict__ bias,
                                                   void* __restrict__ hout,
                                                   float* __restrict__ psum,
                                                   const int* __restrict__ batch) {
  __shared__ __align__(16) uint16_t As[BN * LDA];    // 148480 B
  int t = threadIdx.x;
  int w = __builtin_amdgcn_readfirstlane(t >> 6);    // 0..15
  int L = t & 63;
  int quad = L >> 4, l16 = L & 15;
  int node0 = blockIdx.x * BN;
  int voff = 2 * L;                                  // short offset of this lane's dims
  int kh = w & 3, nt = (w >> 2) & 1, mh = w >> 3;

  // zero A tile: 64*1160 = 74240 shorts = 9280 b128 chunks over 1024 threads
  {
    bf16x8 z = 0;
    #pragma unroll
    for (int i = 0; i < 9; ++i) ((bf16x8*)As)[i * 1024 + t] = z;
    if (t < 64) ((bf16x8*)As)[9 * 1024 + t] = z;
  }

  // hoist first B-frag set (kc=0 of this wave's K-quarter): in flight across phase 1, L2-hot
  const uint16_t* wpk = Wf + (size_t)(kh * 72 + nt * 4) * 512 + (size_t)L * 8;
  bf16x8 bc0 = *(const bf16x8*)(wpk);
  bf16x8 bc1 = *(const bf16x8*)(wpk + 512);
  bf16x8 bc2 = *(const bf16x8*)(wpk + 1024);
  bf16x8 bc3 = *(const bf16x8*)(wpk + 1536);

  __syncthreads();

  // ---- phase 1 ----
  // root slabs: wave w copies rows w*4..w*4+3 (coalesced, overlaps edge streaming)
  #pragma unroll
  for (int ni = 0; ni < 4; ++ni) {
    int r = w * 4 + ni;
    int n = node0 + r;
    if (n < N_NODES)
      *(uint32_t*)(As + (size_t)r * LDA + R_REL * HID + voff) =
          *(const uint32_t*)(hin + (size_t)n * HID + voff);
  }

  {
    int s0 = offs8[node0 * R_REL];
    int blkEnd = ends[blockIdx.x];
    int ce = blkEnd - s0;
    int e0 = s0 + ((ce * w) >> 4);
    int e1 = s0 + ((ce * (w + 1)) >> 4);
    uint32_t kskip = 0xFFFFFFFEu;
    if (e0 > s0) kskip = epack[e0 - 1] >> 16;        // uniform scalar load
    uint32_t cur = 0xFFFFFFFFu;
    float ax = 0.f, ay = 0.f; int ct = 0;
    bool done = false;
    int lsel = L & 15;
    uint32_t svA[16], vvA[16], svB[16], vvB[16];
    uint32_t pvA = epack[e0 + lsel];                 // raw batch 0 (pad covers overrun)
    uint32_t pvB = epack[e0 + 16 + lsel];            // raw batch 1
    EXTGATH(pvA, svA, vvA);                          // batch 0 gathers in flight
    pvA = epack[e0 + 32 + lsel];                     // raw batch 2
    int g = e0;
    while (g < blkEnd && !done) {
      EXTGATH(pvB, svB, vvB);                        // batch k+1 gathers in flight
      pvB = epack[g + 48 + lsel];                    // raw batch k+3
      PROCESS(svA, vvA, g);                          // batch k (gathers landed last iter)
      g += 16;
      if (g >= blkEnd || done) break;
      EXTGATH(pvA, svA, vvA);
      pvA = epack[g + 48 + lsel];
      PROCESS(svB, vvB, g);
      g += 16;
    }
    if (cur != 0xFFFFFFFFu) {
      float iv = __builtin_amdgcn_rcpf((float)ct);
      *(uint32_t*)(As + (size_t)(cur >> 3) * LDA + (cur & 7u) * HID + voff) =
          pack2bf(ax * iv, ay * iv);
    }
  }
  __syncthreads();

  // ---- phase 2: GEMM. wave (mh,nt,kh): rows mh*32..+32 x cols nt*64..+64, 9 kc ----
  f32x4 acc[2][4];
  #pragma unroll
  for (int m = 0; m < 2; ++m)
    #pragma unroll
    for (int j = 0; j < 4; ++j) acc[m][j] = (f32x4){0.f, 0.f, 0.f, 0.f};
  {
    const uint16_t* apk = As + (size_t)(mh * 32 + l16) * LDA + quad * 8 + kh * 9 * 32;
    #pragma unroll 1
    for (int kc = 0; kc < 9; ++kc) {
      int kn = (kc < 8) ? kc + 1 : 8;
      const uint16_t* wn = wpk + (size_t)kn * 4096;
      bf16x8 bn0 = *(const bf16x8*)(wn);
      bf16x8 bn1 = *(const bf16x8*)(wn + 512);
      bf16x8 bn2 = *(const bf16x8*)(wn + 1024);
      bf16x8 bn3 = *(const bf16x8*)(wn + 1536);
      bf16x8 a0 = *(const bf16x8*)(apk + kc * 32);
      bf16x8 a1 = *(const bf16x8*)(apk + kc * 32 + 16 * LDA);
      acc[0][0] = MFMA(a0, bc0, acc[0][0]);
      acc[0][1] = MFMA(a0, bc1, acc[0][1]);
      acc[0][2] = MFMA(a0, bc2, acc[0][2]);
      acc[0][3] = MFMA(a0, bc3, acc[0][3]);
      acc[1][0] = MFMA(a1, bc0, acc[1][0]);
      acc[1][1] = MFMA(a1, bc1, acc[1][1]);
      acc[1][2] = MFMA(a1, bc2, acc[1][2]);
      acc[1][3] = MFMA(a1, bc3, acc[1][3]);
      bc0 = bn0; bc1 = bn1; bc2 = bn2; bc3 = bn3;
    }
  }

  // ---- 4-way split-K reduce via As reused as scratch (dead after A-reads) ----
  float* scratch = (float*)As;
  __syncthreads();
  if (kh != 0) {
    float* sp = scratch + (size_t)(kh - 1) * 8192;
    #pragma unroll
    for (int m = 0; m < 2; ++m)
      #pragma unroll
      for (int j = 0; j < 4; ++j)
        *(f32x4*)(sp + (size_t)((mh * 2 + m) * 8 + nt * 4 + j) * 256 + L * 4) = acc[m][j];
  }
  __syncthreads();
  if (kh == 0) {
    #pragma unroll
    for (int c = 0; c < 3; ++c) {
      const float* sp = scratch + (size_t)c * 8192;
      #pragma unroll
      for (int m = 0; m < 2; ++m)
        #pragma unroll
        for (int j = 0; j < 4; ++j)
          acc[m][j] += *(const f32x4*)(sp + (size_t)((mh * 2 + m) * 8 + nt * 4 + j) * 256 + L * 4);
    }

    // epilogue: C/D layout col=lane&15, row=quad*4+reg
    if (MODE == 0) {
      #pragma unroll
      for (int j = 0; j < 4; ++j) {
        int col = nt * 64 + j * 16 + l16;
        float bv = bias[col];
        #pragma unroll
        for (int m = 0; m < 2; ++m) {
          #pragma unroll
          for (int rg = 0; rg < 4; ++rg) {
            int row = node0 + mh * 32 + m * 16 + quad * 4 + rg;
            if (row < N_NODES)
              ((uint16_t*)hout)[(size_t)row * HID + col] = f2bf(fmaxf(acc[m][j][rg] + bv, 0.f));
          }
        }
      }
    } else {
      // fused global-mean-pool partials (sum; divide in k_final)
      bool fast = false;
      int gA = 0;
      if (node0 + BN <= N_NODES) {
        gA = batch[node0];
        fast = (batch[node0 + BN - 1] == gA);
      }
      if (fast) {
        #pragma unroll
        for (int j = 0; j < 4; ++j) {
          int col = nt * 64 + j * 16 + l16;
          float bv = bias[col];
          float s = 0.f;
          #pragma unroll
          for (int m = 0; m < 2; ++m)
            #pragma unroll
            for (int rg = 0; rg < 4; ++rg) s += fmaxf(acc[m][j][rg] + bv, 0.f);
          s += __shfl_xor(s, 16);
          s += __shfl_xor(s, 32);
          if (quad == 0) atomicAdd(&psum[gA * HID + col], s);
        }
      } else {
        int colb = nt * 64 + l16;
        float bv0 = bias[colb], bv1 = bias[colb + 16], bv2 = bias[colb + 32], bv3 = bias[colb + 48];
        int gp = -1;
        float r0 = 0.f, r1 = 0.f, r2 = 0.f, r3 = 0.f;
        #pragma unroll
        for (int k = 0; k < 8; ++k) {
          int m = k >> 2, rg = k & 3;
          int row = node0 + mh * 32 + m * 16 + quad * 4 + rg;
          if (row < N_NODES) {
            int gg = batch[row];
            if (gg != gp) {
              if (gp >= 0) {
                atomicAdd(&psum[gp * HID + colb],      r0);
                atomicAdd(&psum[gp * HID + colb + 16], r1);
                atomicAdd(&psum[gp * HID + colb + 32], r2);
                atomicAdd(&psum[gp * HID + colb + 48], r3);
              }
              r0 = r1 = r2 = r3 = 0.f; gp = gg;
            }
            r0 += fmaxf(acc[m][0][rg] + bv0, 0.f);
            r1 += fmaxf(acc[m][1][rg] + bv1, 0.f);
            r2 += fmaxf(acc[m][2][rg] + bv2, 0.f);
            r3 += fmaxf(acc[m][3][rg] + bv3, 0.f);
          }
        }
        if (gp >= 0) {
          atomicAdd(&psum[gp * HID + colb],      r0);
          atomicAdd(&psum[gp * HID + colb + 16], r1);
          atomicAdd(&psum[gp * HID + colb + 32], r2);
          atomicAdd(&psum[gp * HID + colb + 48], r3);
        }
      }
    }
  }
}

__global__ __launch_bounds__(1024) void k_final(const float* __restrict__ psum,
                                                const int* __restrict__ gs, const int* __restrict__ ge,
                                                const float* __restrict__ linW, const float* __restrict__ linb,
                                                float* __restrict__ out) {
  __shared__ float lp[NUM_GRAPHS * HID];       // 32 KB
  __shared__ float lw[HID * NUM_CLASSES];      // 8 KB
  int i = threadIdx.x;
  #pragma unroll
  for (int j = 0; j < 8; ++j) lp[j * 1024 + i] = psum[j * 1024 + i];
  #pragma unroll
  for (int j = 0; j < 2; ++j) lw[j * 1024 + i] = linW[j * 1024 + i];
  __syncthreads();
  int g = i >> 4, c = i & 15;
  float inv = 1.f / fmaxf((float)(ge[g] - gs[g]), 1.f);
  float s = 0.f;
  #pragma unroll 8
  for (int k = 0; k < HID; ++k) s += lp[g * HID + k] * lw[k * NUM_CLASSES + c];
  out[i] = s * inv + linb[c];
}

// ---------- launch ----------
extern "C" void kernel_launch(void* const* d_in, const int* in_sizes, int n_in,
                              void* d_out, int out_size, void* d_ws, size_t ws_size,
                              hipStream_t stream) {
  const float* x     = (const float*)d_in[0];
  const int*   ei    = (const int*)d_in[1];   // [2,E]: [0..E) src, [E..2E) dst
  const int*   et    = (const int*)d_in[2];
  const int*   batch = (const int*)d_in[3];
  const float* W1    = (const float*)d_in[4];
  const float* root1 = (const float*)d_in[5];
  const float* b1    = (const float*)d_in[6];
  const float* W2    = (const float*)d_in[7];
  const float* root2 = (const float*)d_in[8];
  const float* b2    = (const float*)d_in[9];
  const float* linW  = (const float*)d_in[10];
  const float* linb  = (const float*)d_in[11];
  float* out = (float*)d_out;

  char* ws = (char*)d_ws;
  size_t off = 0;
  auto alloc = [&](size_t bytes) -> char* {
    char* p = ws + off;
    off += (bytes + 255) & ~(size_t)255;
    return p;
  };
  // zero-region: deg8 | gb | psum | gcount (contiguous, one memset)
  int*      deg8   = (int*)alloc((size_t)N8 * 4);
  int*      gb     = (int*)alloc(2 * NUM_GRAPHS * 4);
  float*    psum   = (float*)alloc((size_t)NUM_GRAPHS * HID * 4);
  int*      gcount = (int*)alloc(4);
  size_t zbytes = (size_t)N8 * 4 + 512 + (size_t)NUM_GRAPHS * HID * 4 + 256;
  int*      gs    = gb;
  int*      ge    = gb + NUM_GRAPHS;
  int*      offs8 = (int*)alloc((size_t)N8 * 4);
  int*      nxt   = (int*)alloc((size_t)N8 * 4);
  int*      ends  = (int*)alloc((size_t)NBLK * 4);
  uint32_t* epack = (uint32_t*)alloc((size_t)(N_EDGES + 80) * 4);   // +80: prefetch overrun pad
  uint16_t* Wf1   = (uint16_t*)alloc((size_t)KOUT * KIN * 2);
  uint16_t* Wf2   = (uint16_t*)alloc((size_t)KOUT * KIN * 2);
  uint16_t* xb    = (uint16_t*)alloc((size_t)N_NODES * HID * 2);
  uint16_t* h1b   = (uint16_t*)alloc((size_t)N_NODES * HID * 2);

  hipMemsetAsync(deg8, 0, zbytes, stream);

  int nb = (N8 + 1023) / 1024;          // 391
  k_prep<<<HIST_B + BND_B + WP_B + CVT_B, 256, 0, stream>>>(
      ei, et, deg8, batch, gs, ge, W1, root1, Wf1, W2, root2, Wf2, x, xb);
  k_scan<<<nb, 256, 0, stream>>>(deg8, offs8, nxt, ends, gcount);
  k_scatter<<<(N_EDGES + 255) / 256, 256, 0, stream>>>(ei, et, nxt, epack);

  // fused layers: sorted-stream aggregate -> As[64,1152] in LDS -> split-K MFMA with Wcat
  k_fused<0><<<NBLK, 1024, 0, stream>>>(xb,  epack, offs8, ends, Wf1, b1, h1b, nullptr, nullptr);
  k_fused<1><<<NBLK, 1024, 0, stream>>>(h1b, epack, offs8, ends, Wf2, b2, nullptr, psum, batch);

  k_final<<<1, 1024, 0, stream>>>(psum, gs, ge, linW, linb, out);
}

// Round 10
// 327.020 us; speedup vs baseline: 1.0882x; 1.0882x over previous
//
#include <hip/hip_runtime.h>
#include <hip/hip_bf16.h>
#include <stdint.h>

#define N_NODES 50000
#define N_EDGES 500000
#define R_REL 8
#define HID 128
#define KIN 128              // input features per slab
#define KOUT 1152            // 9*128: concat K dim (W_0..W_7 | root)
#define N8 400000            // N_NODES * R_REL composite buckets
#define NUM_GRAPHS 64
#define NUM_CLASSES 16

#define BN 32                // dst-nodes per fused block
#define LDA 1160             // A row stride in shorts (2320 B)
#define NBLK 1563            // ceil(50000/32)

typedef __attribute__((ext_vector_type(8))) short bf16x8;
typedef __attribute__((ext_vector_type(4))) float f32x4;

// ---------- helpers ----------
__device__ __forceinline__ uint16_t f2bf(float f) {
  uint32_t u = __float_as_uint(f);
  u += 0x7FFFu + ((u >> 16) & 1u);   // RNE
  return (uint16_t)(u >> 16);
}
__device__ __forceinline__ float bf2f(uint32_t b) {
  return __uint_as_float(b << 16);
}
__device__ __forceinline__ uint32_t pack2bf(float a, float b) {
  return (uint32_t)f2bf(a) | ((uint32_t)f2bf(b) << 16);
}
#define MFMA(a, b, c) __builtin_amdgcn_mfma_f32_16x16x32_bf16((a), (b), (c), 0, 0, 0)

// ---------- merged prep: hist | bounds | weightprep (LDS-staged) | x->bf16 ----------
#define HIST_B 1954
#define BND_B 196
#define WP_B 72             // 2 matrices x 36 kc-chunks
#define CVT_B 3125          // N_NODES*HID/8 / 256
__global__ __launch_bounds__(256) void k_prep(const int* __restrict__ ei, const int* __restrict__ et,
                                              int* __restrict__ deg8,
                                              const int* __restrict__ batch,
                                              int* __restrict__ gs, int* __restrict__ ge,
                                              const float* __restrict__ W1, const float* __restrict__ root1,
                                              uint16_t* __restrict__ Wf1,
                                              const float* __restrict__ W2, const float* __restrict__ root2,
                                              uint16_t* __restrict__ Wf2,
                                              const float* __restrict__ x, uint16_t* __restrict__ xb) {
  int b = blockIdx.x;
  int t = threadIdx.x;
  if (b < HIST_B) {                                 // (dst,rel) edge histogram (400K buckets)
    int i = b * 256 + t;
    if (i < N_EDGES) atomicAdd(&deg8[ei[N_EDGES + i] * R_REL + et[i]], 1);
    return;
  }
  b -= HIST_B;
  if (b < BND_B) {                                  // graph boundaries (batch sorted)
    int i = b * 256 + t;
    if (i < N_NODES) {
      int g = batch[i];
      if (i == 0) gs[g] = 0;
      else { int pg = batch[i - 1]; if (pg != g) { ge[pg] = i; gs[g] = i; } }
      if (i == N_NODES - 1) ge[g] = N_NODES;
    }
    return;
  }
  b -= BND_B;
  if (b < WP_B) {
    // weight prep, LDS-staged: block handles one kc-chunk (32 K-rows x 128 cols) of one matrix.
    __shared__ float lw[32 * 129];
    const float* W    = (b < 36) ? W1 : W2;
    const float* root = (b < 36) ? root1 : root2;
    uint16_t*    Wf   = (b < 36) ? Wf1 : Wf2;
    int kc = (b < 36) ? b : b - 36;
    #pragma unroll
    for (int j = 0; j < 4; ++j) {
      int fi = j * 256 + t;                  // float4 slot over 32 rows x 32 f4
      int row = fi >> 5, c4 = fi & 31;
      int kk = kc * 32 + row;
      int s = kk >> 7, k = kk & 127;
      const float* src = (s < R_REL) ? (W + ((size_t)s * KIN + k) * HID) : (root + (size_t)k * HID);
      float4 v = *(const float4*)(src + c4 * 4);
      lw[row * 129 + c4 * 4 + 0] = v.x;
      lw[row * 129 + c4 * 4 + 1] = v.y;
      lw[row * 129 + c4 * 4 + 2] = v.z;
      lw[row * 129 + c4 * 4 + 3] = v.w;
    }
    __syncthreads();
    #pragma unroll
    for (int p = 0; p < 2; ++p) {
      int slot = p * 256 + t;                // 8 frags x 64 lanes
      int nt = slot >> 6, L = slot & 63;
      int quad = L >> 4, l16 = L & 15;
      uint16_t tmp[8];
      #pragma unroll
      for (int e = 0; e < 8; ++e)
        tmp[e] = f2bf(lw[(quad * 8 + e) * 129 + nt * 16 + l16]);
      uint4 o;
      o.x = (uint32_t)tmp[0] | ((uint32_t)tmp[1] << 16);
      o.y = (uint32_t)tmp[2] | ((uint32_t)tmp[3] << 16);
      o.z = (uint32_t)tmp[4] | ((uint32_t)tmp[5] << 16);
      o.w = (uint32_t)tmp[6] | ((uint32_t)tmp[7] << 16);
      *(uint4*)(Wf + ((size_t)(kc * 8 + nt) * 512 + (size_t)L * 8)) = o;
    }
    return;
  }
  b -= WP_B;
  {                                                 // x (fp32) -> xb (bf16), 8 elems/thread
    int i = b * 256 + t;                            // < 800000 exact
    const float4* p = (const float4*)x + (size_t)i * 2;
    float4 a = p[0], c = p[1];
    uint4 o;
    o.x = pack2bf(a.x, a.y); o.y = pack2bf(a.z, a.w);
    o.z = pack2bf(c.x, c.y); o.w = pack2bf(c.z, c.w);
    *(uint4*)(xb + (size_t)i * 8) = o;
  }
}

// ---------- single-kernel scan over 400K (dst,rel) buckets ----------
// Order-free global base via one atomicAdd per block: bucket ranges are permuted across
// 1024-bucket chunks, but each fused block's 256 buckets live inside ONE chunk, so
// within-block contiguity+ordering is preserved. Per-fused-block end offsets -> ends[].
__global__ __launch_bounds__(256) void k_scan(const int* __restrict__ deg8, int* __restrict__ offs8,
                                              int* __restrict__ nxt, int* __restrict__ ends,
                                              int* __restrict__ gcount) {
  __shared__ int sh[256];
  __shared__ int base_sh;
  int t = threadIdx.x;
  int base = blockIdx.x * 1024 + t * 4;
  int v[4]; int s = 0;
  #pragma unroll
  for (int i = 0; i < 4; ++i) { int idx = base + i; v[i] = (idx < N8) ? deg8[idx] : 0; s += v[i]; }
  sh[t] = s;
  __syncthreads();
  for (int d = 1; d < 256; d <<= 1) {
    int add = (t >= d) ? sh[t - d] : 0;
    __syncthreads();
    sh[t] += add;
    __syncthreads();
  }
  if (t == 0) base_sh = atomicAdd(gcount, sh[255]);
  __syncthreads();
  int gbase = base_sh;
  int run = gbase + sh[t] - s;
  #pragma unroll
  for (int i = 0; i < 4; ++i) {
    int idx = base + i;
    if (idx < N8) { offs8[idx] = run; nxt[idx] = run; }
    run += v[i];
  }
  // fused-block ends: this chunk = fused blocks 4b..4b+3 (256 buckets each)
  if ((t & 63) == 63) {
    int fb = 4 * blockIdx.x + (t >> 6);
    if (fb < NBLK) ends[fb] = gbase + sh[t];
  }
}

// scatter into (dst,rel) buckets: within each fused block the stream is (dst,rel)-grouped.
// epack = src | rel<<16 | (dst&31)<<19
__global__ __launch_bounds__(256) void k_scatter(const int* __restrict__ ei, const int* __restrict__ et,
                                                 int* __restrict__ nxt, uint32_t* __restrict__ epack) {
  int i = blockIdx.x * 256 + threadIdx.x;
  if (i < N_EDGES) {
    int rel = et[i];
    int dst = ei[N_EDGES + i];
    int p = atomicAdd(&nxt[dst * R_REL + rel], 1);
    epack[p] = (uint32_t)ei[i] | ((uint32_t)rel << 16) | ((uint32_t)(dst & 31) << 19);
  }
}

// ---------- phase-1 macros: branch-free extract+gather, scalar-branch accumulate ----------
#define EXTGATH(pc, sv, vv)                                                   \
  {                                                                           \
    _Pragma("unroll")                                                         \
    for (int i_ = 0; i_ < 16; ++i_)                                           \
      sv[i_] = (uint32_t)__builtin_amdgcn_readlane((int)(pc), i_);            \
    _Pragma("unroll")                                                         \
    for (int i_ = 0; i_ < 16; ++i_) {                                         \
      uint32_t s_ = sv[i_] & 0xFFFFu;                                         \
      s_ = (s_ < (uint32_t)N_NODES) ? s_ : 0u;                                \
      vv[i_] = *(const uint32_t*)(hin + (size_t)s_ * HID + voff);             \
    }                                                                         \
    __builtin_amdgcn_sched_barrier(0);                                        \
  }

#define PROCESS(sv, vv, gbase_)                                               \
  {                                                                           \
    int m_ = min(16, blkEnd - (gbase_));                                      \
    _Pragma("unroll")                                                         \
    for (int i_ = 0; i_ < 16; ++i_) {                                         \
      if (i_ >= m_) break;                                                    \
      uint32_t k_ = sv[i_] >> 16;                                             \
      if (k_ == cur) {                                                        \
        uint32_t v_ = vv[i_];                                                 \
        ax += bf2f(v_ & 0xFFFFu); ay += bf2f(v_ >> 16); ++ct;                 \
      } else if (k_ != kskip) {                                               \
        if (cur != 0xFFFFFFFFu) {                                             \
          float iv_ = __builtin_amdgcn_rcpf((float)ct);                       \
          *(uint32_t*)(As + (size_t)(cur >> 3) * LDA + (cur & 7u) * HID + voff) = \
              pack2bf(ax * iv_, ay * iv_);                                    \
        }                                                                     \
        if ((gbase_) + i_ >= e1) { done = true; cur = 0xFFFFFFFFu; break; }   \
        cur = k_;                                                             \
        uint32_t v_ = vv[i_];                                                 \
        ax = bf2f(v_ & 0xFFFFu); ay = bf2f(v_ >> 16); ct = 1;                 \
      }                                                                       \
    }                                                                         \
  }

// ---------- fused layer: sorted-stream aggregate -> split-K MFMA transform ----------
// Block = 32 dst nodes, 1024 threads (16 waves), LDS As[32][1160] bf16 (74240 B).
// 2 blocks/CU x 16 waves = 32 waves/CU (VGPR ~64 with pipeline; 64 x 8 waves = full RF).
// Phase 1: 16 waves stream the block's edge range [offs8[blk*256], ends[blk]) in flat
//   chunks with a 2-stage ping-pong pipeline: batch k+1's 16 gathers issue
//   (sched_barrier-pinned) while batch k is processed. Scalar-branch flush-on-key-change
//   (key = (loc<<3)|rel), mean 1/cnt at flush.
// Phase 2: split-K GEMM: wave = (nt = w&7, kh = w>>3); 18 kc each, depth-2 B prefetch;
//   kh-halves reduced through the As region reused as scratch (dead after A-reads).
// MODE 0: write bf16 hout. MODE 1: fused global-mean-pool partials into psum.
template<int MODE>
__global__ __launch_bounds__(1024, 4) void k_fused(const uint16_t* __restrict__ hin,
                                                   const uint32_t* __restrict__ epack,
                                                   const int* __restrict__ offs8,
                                                   const int* __restrict__ ends,
                                                   const uint16_t* __restrict__ Wf,
                                                   const float* __restrict__ bias,
                                                   void* __restrict__ hout,
                                                   float* __restrict__ psum,
                                                   const int* __restrict__ batch) {
  __shared__ __align__(16) uint16_t As[BN * LDA];    // 74240 B
  int t = threadIdx.x;
  int w = __builtin_amdgcn_readfirstlane(t >> 6);    // 0..15
  int L = t & 63;
  int quad = L >> 4, l16 = L & 15;
  int node0 = blockIdx.x * BN;
  int voff = 2 * L;                                  // short offset of this lane's dims
  int nt = w & 7, kh = w >> 3;

  // zero A tile: 32*1160 = 37120 shorts = 4640 b128 chunks over 1024 threads
  {
    bf16x8 z = 0;
    #pragma unroll
    for (int i = 0; i < 4; ++i) ((bf16x8*)As)[i * 1024 + t] = z;
    if (t < 544) ((bf16x8*)As)[4 * 1024 + t] = z;
  }

  // hoist depth-2 B prefetch across the aggregation phase (same addrs every block: L2-hot)
  const uint16_t* wpk = Wf + ((size_t)(kh * 18 * 8 + nt)) * 512 + (size_t)L * 8;
  bf16x8 b0 = *(const bf16x8*)(wpk);
  bf16x8 b1 = *(const bf16x8*)(wpk + 4096);

  __syncthreads();

  // ---- phase 1 ----
  // root slabs: wave w copies rows w*2..w*2+1 (coalesced, overlaps edge streaming)
  #pragma unroll
  for (int ni = 0; ni < 2; ++ni) {
    int r = w * 2 + ni;
    int n = node0 + r;
    if (n < N_NODES)
      *(uint32_t*)(As + (size_t)r * LDA + R_REL * HID + voff) =
          *(const uint32_t*)(hin + (size_t)n * HID + voff);
  }

  {
    int s0 = offs8[node0 * R_REL];
    int blkEnd = ends[blockIdx.x];
    int ce = blkEnd - s0;
    int e0 = s0 + ((ce * w) >> 4);
    int e1 = s0 + ((ce * (w + 1)) >> 4);
    uint32_t kskip = 0xFFFFFFFEu;
    if (e0 > s0) kskip = epack[e0 - 1] >> 16;        // uniform scalar load
    uint32_t cur = 0xFFFFFFFFu;
    float ax = 0.f, ay = 0.f; int ct = 0;
    bool done = false;
    int lsel = L & 15;
    uint32_t svA[16], vvA[16], svB[16], vvB[16];
    uint32_t pvA = epack[e0 + lsel];                 // raw batch 0 (pad covers overrun)
    uint32_t pvB = epack[e0 + 16 + lsel];            // raw batch 1
    EXTGATH(pvA, svA, vvA);                          // batch 0 gathers in flight
    pvA = epack[e0 + 32 + lsel];                     // raw batch 2
    int g = e0;
    while (g < blkEnd && !done) {
      EXTGATH(pvB, svB, vvB);                        // batch k+1 gathers in flight
      pvB = epack[g + 48 + lsel];                    // raw batch k+3
      PROCESS(svA, vvA, g);                          // batch k (gathers landed last iter)
      g += 16;
      if (g >= blkEnd || done) break;
      EXTGATH(pvA, svA, vvA);
      pvA = epack[g + 48 + lsel];
      PROCESS(svB, vvB, g);
      g += 16;
    }
    if (cur != 0xFFFFFFFFu) {
      float iv = __builtin_amdgcn_rcpf((float)ct);
      *(uint32_t*)(As + (size_t)(cur >> 3) * LDA + (cur & 7u) * HID + voff) =
          pack2bf(ax * iv, ay * iv);
    }
  }
  __syncthreads();

  // ---- phase 2: split-K GEMM. wave (nt,kh): rows 0..32 x cols [nt*16,nt*16+16), K-half kh ----
  f32x4 acc0 = (f32x4){0.f, 0.f, 0.f, 0.f};
  f32x4 acc1 = (f32x4){0.f, 0.f, 0.f, 0.f};
  {
    const uint16_t* apk = As + (size_t)l16 * LDA + quad * 8 + kh * 18 * 32;
    bf16x8 a00 = *(const bf16x8*)(apk);
    bf16x8 a01 = *(const bf16x8*)(apk + 16 * LDA);
    #pragma unroll 1
    for (int kc = 0; kc < 16; kc += 2) {
      bf16x8 nb0 = *(const bf16x8*)(wpk + (size_t)(kc + 2) * 4096);
      bf16x8 na0 = *(const bf16x8*)(apk + (kc + 1) * 32);
      bf16x8 na1 = *(const bf16x8*)(apk + (kc + 1) * 32 + 16 * LDA);
      acc0 = MFMA(a00, b0, acc0);
      acc1 = MFMA(a01, b0, acc1);
      b0 = nb0;
      bf16x8 nb1 = *(const bf16x8*)(wpk + (size_t)(kc + 3) * 4096);
      bf16x8 ma0 = *(const bf16x8*)(apk + (kc + 2) * 32);
      bf16x8 ma1 = *(const bf16x8*)(apk + (kc + 2) * 32 + 16 * LDA);
      acc0 = MFMA(na0, b1, acc0);
      acc1 = MFMA(na1, b1, acc1);
      b1 = nb1; a00 = ma0; a01 = ma1;
    }
    bf16x8 ta0 = *(const bf16x8*)(apk + 17 * 32);
    bf16x8 ta1 = *(const bf16x8*)(apk + 17 * 32 + 16 * LDA);
    acc0 = MFMA(a00, b0, acc0);
    acc1 = MFMA(a01, b0, acc1);
    acc0 = MFMA(ta0, b1, acc0);
    acc1 = MFMA(ta1, b1, acc1);
  }

  // ---- split-K reduce via As reused as scratch (dead after A-reads) ----
  float* scratch = (float*)As;
  __syncthreads();
  if (kh == 1) {
    float* sp = scratch + (size_t)(nt * 2) * 256 + L * 4;
    *(f32x4*)(sp) = acc0;
    *(f32x4*)(sp + 256) = acc1;
  }
  __syncthreads();
  if (kh == 0) {
    const float* sp = scratch + (size_t)(nt * 2) * 256 + L * 4;
    acc0 += *(const f32x4*)(sp);
    acc1 += *(const f32x4*)(sp + 256);

    // epilogue: C/D layout col=lane&15, row=quad*4+reg
    int col = nt * 16 + l16;
    float bv = bias[col];
    if (MODE == 0) {
      #pragma unroll
      for (int rg = 0; rg < 4; ++rg) {
        int row = node0 + quad * 4 + rg;
        if (row < N_NODES)
          ((uint16_t*)hout)[(size_t)row * HID + col] = f2bf(fmaxf(acc0[rg] + bv, 0.f));
      }
      #pragma unroll
      for (int rg = 0; rg < 4; ++rg) {
        int row = node0 + 16 + quad * 4 + rg;
        if (row < N_NODES)
          ((uint16_t*)hout)[(size_t)row * HID + col] = f2bf(fmaxf(acc1[rg] + bv, 0.f));
      }
    } else {
      // fused global-mean-pool partials (sum; divide in k_final)
      bool fast = false;
      int gA = 0;
      if (node0 + BN <= N_NODES) {
        gA = batch[node0];
        fast = (batch[node0 + BN - 1] == gA);
      }
      if (fast) {
        float s = 0.f;
        #pragma unroll
        for (int rg = 0; rg < 4; ++rg) s += fmaxf(acc0[rg] + bv, 0.f);
        #pragma unroll
        for (int rg = 0; rg < 4; ++rg) s += fmaxf(acc1[rg] + bv, 0.f);
        s += __shfl_xor(s, 16);
        s += __shfl_xor(s, 32);
        if (quad == 0) atomicAdd(&psum[gA * HID + col], s);
      } else {
        int gp = -1; float run = 0.f;
        #pragma unroll
        for (int k = 0; k < 8; ++k) {
          int rg = k & 3;
          int row = node0 + (k >> 2) * 16 + quad * 4 + rg;
          float v = (k < 4) ? acc0[rg] : acc1[rg];
          if (row < N_NODES) {
            int gg = batch[row];
            if (gg != gp) {
              if (gp >= 0) atomicAdd(&psum[gp * HID + col], run);
              run = 0.f; gp = gg;
            }
            run += fmaxf(v + bv, 0.f);
          }
        }
        if (gp >= 0) atomicAdd(&psum[gp * HID + col], run);
      }
    }
  }
}

__global__ __launch_bounds__(1024) void k_final(const float* __restrict__ psum,
                                                const int* __restrict__ gs, const int* __restrict__ ge,
                                                const float* __restrict__ linW, const float* __restrict__ linb,
                                                float* __restrict__ out) {
  __shared__ float lp[NUM_GRAPHS * HID];       // 32 KB
  __shared__ float lw[HID * NUM_CLASSES];      // 8 KB
  int i = threadIdx.x;
  #pragma unroll
  for (int j = 0; j < 8; ++j) lp[j * 1024 + i] = psum[j * 1024 + i];
  #pragma unroll
  for (int j = 0; j < 2; ++j) lw[j * 1024 + i] = linW[j * 1024 + i];
  __syncthreads();
  int g = i >> 4, c = i & 15;
  float inv = 1.f / fmaxf((float)(ge[g] - gs[g]), 1.f);
  float s = 0.f;
  #pragma unroll 8
  for (int k = 0; k < HID; ++k) s += lp[g * HID + k] * lw[k * NUM_CLASSES + c];
  out[i] = s * inv + linb[c];
}

// ---------- launch ----------
extern "C" void kernel_launch(void* const* d_in, const int* in_sizes, int n_in,
                              void* d_out, int out_size, void* d_ws, size_t ws_size,
                              hipStream_t stream) {
  const float* x     = (const float*)d_in[0];
  const int*   ei    = (const int*)d_in[1];   // [2,E]: [0..E) src, [E..2E) dst
  const int*   et    = (const int*)d_in[2];
  const int*   batch = (const int*)d_in[3];
  const float* W1    = (const float*)d_in[4];
  const float* root1 = (const float*)d_in[5];
  const float* b1    = (const float*)d_in[6];
  const float* W2    = (const float*)d_in[7];
  const float* root2 = (const float*)d_in[8];
  const float* b2    = (const float*)d_in[9];
  const float* linW  = (const float*)d_in[10];
  const float* linb  = (const float*)d_in[11];
  float* out = (float*)d_out;

  char* ws = (char*)d_ws;
  size_t off = 0;
  auto alloc = [&](size_t bytes) -> char* {
    char* p = ws + off;
    off += (bytes + 255) & ~(size_t)255;
    return p;
  };
  // zero-region: deg8 | gb | psum | gcount (contiguous, one memset)
  int*      deg8   = (int*)alloc((size_t)N8 * 4);
  int*      gb     = (int*)alloc(2 * NUM_GRAPHS * 4);
  float*    psum   = (float*)alloc((size_t)NUM_GRAPHS * HID * 4);
  int*      gcount = (int*)alloc(4);
  size_t zbytes = (size_t)N8 * 4 + 512 + (size_t)NUM_GRAPHS * HID * 4 + 256;
  int*      gs    = gb;
  int*      ge    = gb + NUM_GRAPHS;
  int*      offs8 = (int*)alloc((size_t)N8 * 4);
  int*      nxt   = (int*)alloc((size_t)N8 * 4);
  int*      ends  = (int*)alloc((size_t)NBLK * 4);
  uint32_t* epack = (uint32_t*)alloc((size_t)(N_EDGES + 80) * 4);   // +80: prefetch overrun pad
  uint16_t* Wf1   = (uint16_t*)alloc((size_t)KOUT * KIN * 2);
  uint16_t* Wf2   = (uint16_t*)alloc((size_t)KOUT * KIN * 2);
  uint16_t* xb    = (uint16_t*)alloc((size_t)N_NODES * HID * 2);
  uint16_t* h1b   = (uint16_t*)alloc((size_t)N_NODES * HID * 2);

  hipMemsetAsync(deg8, 0, zbytes, stream);

  int nb = (N8 + 1023) / 1024;          // 391
  k_prep<<<HIST_B + BND_B + WP_B + CVT_B, 256, 0, stream>>>(
      ei, et, deg8, batch, gs, ge, W1, root1, Wf1, W2, root2, Wf2, x, xb);
  k_scan<<<nb, 256, 0, stream>>>(deg8, offs8, nxt, ends, gcount);
  k_scatter<<<(N_EDGES + 255) / 256, 256, 0, stream>>>(ei, et, nxt, epack);

  // fused layers: sorted-stream aggregate -> As[32,1152] in LDS -> split-K MFMA with Wcat
  k_fused<0><<<NBLK, 1024, 0, stream>>>(xb,  epack, offs8, ends, Wf1, b1, h1b, nullptr, nullptr);
  k_fused<1><<<NBLK, 1024, 0, stream>>>(h1b, epack, offs8, ends, Wf2, b2, nullptr, psum, batch);

  k_final<<<1, 1024, 0, stream>>>(psum, gs, ge, linW, linb, out);
}